// Round 7
// baseline (67.154 us; speedup 1.0000x reference)
//
#include <hip/hip_runtime.h>
#include <math.h>

// Problem constants (from reference setup_inputs): z_list (P,B,D) fp32
constexpr int P = 64, B = 512, D = 1024;
constexpr int D4 = D / 4;           // 256 float4 per row
constexpr int WAVES = 4;            // waves per block in main kernel
constexpr int PC = P / WAVES;       // 16 p-rows per wave (8 pairs)
constexpr int K3B = 32;             // blocks in S/T partial-sum kernel
constexpr int BPB = B / K3B;        // 16 b's per K3 block
constexpr int REP = 3;              // DIAGNOSTIC: repeat streaming pass to
                                    // surface k_main in rocprof top-5
#define EPS 1e-8f

__device__ inline float wave_reduce_sum(float v) {
#pragma unroll
  for (int off = 1; off < 64; off <<= 1) v += __shfl_xor(v, off);
  return v;
}

__device__ inline float dot4(const float4& a, const float4& b) {
  return a.x * b.x + a.y * b.y + a.z * b.z + a.w * b.w;
}

// K_main: one block (4 waves) per b; R4's pair-streaming structure, repeated
// REP times (results scaled back). Output identical to single pass.
__global__ __launch_bounds__(256) void k_main_rep(const float* __restrict__ z,
                                                  float* __restrict__ an,
                                                  float* __restrict__ Uv,
                                                  float* __restrict__ diag) {
  const int b = blockIdx.x;
  const int t = threadIdx.x;
  const int w = t >> 6;              // wave 0..3
  const int lane = t & 63;

  __shared__ float4 lds_zs[WAVES][D4];  // 16 KB
  __shared__ float4 lds_uu[WAVES][D4];  // 16 KB
  __shared__ float red[2 * WAVES];

  float4 zs[4], uu[4];
#pragma unroll
  for (int k = 0; k < 4; ++k) {
    zs[k] = make_float4(0.f, 0.f, 0.f, 0.f);
    uu[k] = make_float4(0.f, 0.f, 0.f, 0.f);
  }

  // wave w handles p = w*PC .. w*PC+PC-1, rows z[p][b][:]
  const size_t pstride = (size_t)B * D4;  // float4 stride between p's
  const float4* base = (const float4*)z + ((size_t)(w * PC) * B + b) * D4;

  for (int rep = 0; rep < REP; ++rep) {
    float4 curA[4], curB[4];
#pragma unroll
    for (int k = 0; k < 4; ++k) {
      curA[k] = base[k * 64 + lane];
      curB[k] = base[pstride + k * 64 + lane];
    }

    for (int pr = 0; pr < PC / 2; ++pr) {
      float4 nxtA[4], nxtB[4];
      const bool more = (pr + 1 < PC / 2);
      if (more) {
        const float4* nA = base + (size_t)(2 * pr + 2) * pstride;
        const float4* nB = base + (size_t)(2 * pr + 3) * pstride;
#pragma unroll
        for (int k = 0; k < 4; ++k) {
          nxtA[k] = nA[k * 64 + lane];
          nxtB[k] = nB[k * 64 + lane];
        }
      }

      float ssA = 0.f, ssB = 0.f;
#pragma unroll
      for (int k = 0; k < 4; ++k) {
        ssA += dot4(curA[k], curA[k]);
        ssB += dot4(curB[k], curB[k]);
      }
#pragma unroll
      for (int off = 1; off < 64; off <<= 1) {
        ssA += __shfl_xor(ssA, off);
        ssB += __shfl_xor(ssB, off);
      }
      const float wA = 1.0f / fmaxf(sqrtf(ssA), EPS);
      const float wB = 1.0f / fmaxf(sqrtf(ssB), EPS);

#pragma unroll
      for (int k = 0; k < 4; ++k) {
        zs[k].x += curA[k].x + curB[k].x;
        zs[k].y += curA[k].y + curB[k].y;
        zs[k].z += curA[k].z + curB[k].z;
        zs[k].w += curA[k].w + curB[k].w;
        uu[k].x += wA * curA[k].x + wB * curB[k].x;
        uu[k].y += wA * curA[k].y + wB * curB[k].y;
        uu[k].z += wA * curA[k].z + wB * curB[k].z;
        uu[k].w += wA * curA[k].w + wB * curB[k].w;
      }
      if (more) {
#pragma unroll
        for (int k = 0; k < 4; ++k) {
          curA[k] = nxtA[k];
          curB[k] = nxtB[k];
        }
      }
    }
  }

  // cross-wave combine: wave w's float4 index k*64+lane
#pragma unroll
  for (int k = 0; k < 4; ++k) {
    lds_zs[w][k * 64 + lane] = zs[k];
    lds_uu[w][k * 64 + lane] = uu[k];
  }
  __syncthreads();

  // thread t now owns float4 index t (d = 4t..4t+3)
  float4 zsum = make_float4(0.f, 0.f, 0.f, 0.f);
  float4 usum = make_float4(0.f, 0.f, 0.f, 0.f);
#pragma unroll
  for (int ww = 0; ww < WAVES; ++ww) {
    float4 a = lds_zs[ww][t];
    float4 u = lds_uu[ww][t];
    zsum.x += a.x; zsum.y += a.y; zsum.z += a.z; zsum.w += a.w;
    usum.x += u.x; usum.y += u.y; usum.z += u.z; usum.w += u.w;
  }
  // undo the REP-fold accumulation (a4 is scale-invariant; usum must be exact)
  const float repinv = 1.0f / (float)REP;
  usum.x *= repinv; usum.y *= repinv; usum.z *= repinv; usum.w *= repinv;

  // ||z_sum||^2 across the block, broadcast (zsum is REP*true, scale-invariant)
  float ss = dot4(zsum, zsum);
  ss = wave_reduce_sum(ss);
  if (lane == 0) red[w] = ss;
  __syncthreads();
  ss = red[0] + red[1] + red[2] + red[3];

  // an = zsum / max(||zsum||, REP*P*eps)  (scale cancels)
  const float inv = 1.0f / fmaxf(sqrtf(ss), (float)REP * (float)P * EPS);
  float4 a4 = make_float4(zsum.x * inv, zsum.y * inv, zsum.z * inv, zsum.w * inv);

  ((float4*)an)[(size_t)b * D4 + t] = a4;
  ((float4*)Uv)[(size_t)b * D4 + t] = usum;

  float dg = dot4(usum, a4);
  dg = wave_reduce_sum(dg);
  if (lane == 0) red[WAVES + w] = dg;
  __syncthreads();
  if (t == 0) diag[b] = red[WAVES] + red[WAVES + 1] + red[WAVES + 2] + red[WAVES + 3];
}

// K3: partial column-sums of an and Uv over b-chunks -> Spart/Tpart [K3B][D]
__global__ __launch_bounds__(256) void k3_colsum(const float* __restrict__ an,
                                                 const float* __restrict__ Uv,
                                                 float* __restrict__ Spart,
                                                 float* __restrict__ Tpart) {
  const int blk = blockIdx.x;
  const int t = threadIdx.x;
  float4 s = make_float4(0.f, 0.f, 0.f, 0.f);
  float4 tt = make_float4(0.f, 0.f, 0.f, 0.f);
#pragma unroll 4
  for (int i = 0; i < BPB; ++i) {
    const size_t b = (size_t)blk * BPB + i;
    float4 a = ((const float4*)an)[b * D4 + t];
    float4 u = ((const float4*)Uv)[b * D4 + t];
    s.x += a.x; s.y += a.y; s.z += a.z; s.w += a.w;
    tt.x += u.x; tt.y += u.y; tt.z += u.z; tt.w += u.w;
  }
  ((float4*)Spart)[(size_t)blk * D4 + t] = s;
  ((float4*)Tpart)[(size_t)blk * D4 + t] = tt;
}

// K4: final combine. S = sum Spart, T = sum Tpart, out = (S.T - sum diag)/count - 1
__global__ __launch_bounds__(256) void k4_final(const float* __restrict__ Spart,
                                                const float* __restrict__ Tpart,
                                                const float* __restrict__ diag,
                                                float* __restrict__ out) {
  const int t = threadIdx.x;
  __shared__ float red[4];
  float4 S = make_float4(0.f, 0.f, 0.f, 0.f);
  float4 T = make_float4(0.f, 0.f, 0.f, 0.f);
#pragma unroll 4
  for (int blk = 0; blk < K3B; ++blk) {
    float4 s = ((const float4*)Spart)[(size_t)blk * D4 + t];
    float4 u = ((const float4*)Tpart)[(size_t)blk * D4 + t];
    S.x += s.x; S.y += s.y; S.z += s.z; S.w += s.w;
    T.x += u.x; T.y += u.y; T.z += u.z; T.w += u.w;
  }
  float local = dot4(S, T) - diag[t] - diag[t + 256];
  local = wave_reduce_sum(local);
  const int wid = t >> 6;
  if ((t & 63) == 0) red[wid] = local;
  __syncthreads();
  if (t == 0) {
    const float tot = red[0] + red[1] + red[2] + red[3];
    const float count = 64.0f * 512.0f * 511.0f;  // P*B*(B-1), exact in fp32
    out[0] = tot / count - 1.0f;
  }
}

extern "C" void kernel_launch(void* const* d_in, const int* in_sizes, int n_in,
                              void* d_out, int out_size, void* d_ws, size_t ws_size,
                              hipStream_t stream) {
  const float* z = (const float*)d_in[0];  // z_list (P,B,D); d_in[1] unused

  float* ws = (float*)d_ws;
  float* an = ws;                                  // B*D
  float* Uv = an + (size_t)B * D;                  // B*D
  float* diag = Uv + (size_t)B * D;                // B
  float* Spart = diag + B;                         // K3B*D
  float* Tpart = Spart + (size_t)K3B * D;          // K3B*D

  k_main_rep<<<B, 256, 0, stream>>>(z, an, Uv, diag);
  k3_colsum<<<K3B, 256, 0, stream>>>(an, Uv, Spart, Tpart);
  k4_final<<<1, 256, 0, stream>>>(Spart, Tpart, diag, (float*)d_out);
}

// Round 8
// 48.793 us; speedup vs baseline: 1.3763x; 1.3763x over previous
//
#include <hip/hip_runtime.h>
#include <math.h>

// Problem constants (from reference setup_inputs): z_list (P,B,D) fp32
constexpr int P = 64, B = 512, D = 1024;
constexpr int D4 = D / 4;           // 256 float4 per row
constexpr int WAVES = 4;            // waves per block in main kernel
constexpr int PC = P / WAVES;       // 16 p-rows per wave (8 pairs)
constexpr int TB = 32;              // blocks in tail kernel
constexpr int BPB = B / TB;         // 16 b's per tail block
#define EPS 1e-8f

__device__ inline float wave_reduce_sum(float v) {
#pragma unroll
  for (int off = 1; off < 64; off <<= 1) v += __shfl_xor(v, off);
  return v;
}

__device__ inline float dot4(const float4& a, const float4& b) {
  return a.x * b.x + a.y * b.y + a.z * b.z + a.w * b.w;
}

// K_main: one block (4 waves) per b. Each wave streams 16 p-rows of z[:,b,:]
// as 8 row-pairs (depth-1 prefetch, 2 interleaved norm-reduce chains). LDS
// combines the 4 waves; block normalizes mean row -> an[b], writes Uv[b],
// diag[b] = Uv.an. Block 0 also re-zeroes the tail semaphore (replay safety).
// Measured (R7, REP=3): 27.3 us/pass, ~4.9 TB/s effective read BW.
__global__ __launch_bounds__(256) void k_main(const float* __restrict__ z,
                                              float* __restrict__ an,
                                              float* __restrict__ Uv,
                                              float* __restrict__ diag,
                                              int* __restrict__ counter) {
  const int b = blockIdx.x;
  const int t = threadIdx.x;
  const int w = t >> 6;              // wave 0..3
  const int lane = t & 63;

  if (b == 0 && t == 0) *counter = 0;  // visible to k_tail after kernel boundary

  __shared__ float4 lds_zs[WAVES][D4];  // 16 KB
  __shared__ float4 lds_uu[WAVES][D4];  // 16 KB
  __shared__ float red[2 * WAVES];

  float4 zs[4], uu[4];
#pragma unroll
  for (int k = 0; k < 4; ++k) {
    zs[k] = make_float4(0.f, 0.f, 0.f, 0.f);
    uu[k] = make_float4(0.f, 0.f, 0.f, 0.f);
  }

  // wave w handles p = w*PC .. w*PC+PC-1, rows z[p][b][:]
  const size_t pstride = (size_t)B * D4;  // float4 stride between p's
  const float4* base = (const float4*)z + ((size_t)(w * PC) * B + b) * D4;

  float4 curA[4], curB[4];
#pragma unroll
  for (int k = 0; k < 4; ++k) {
    curA[k] = base[k * 64 + lane];
    curB[k] = base[pstride + k * 64 + lane];
  }

  for (int pr = 0; pr < PC / 2; ++pr) {
    float4 nxtA[4], nxtB[4];
    const bool more = (pr + 1 < PC / 2);
    if (more) {
      const float4* nA = base + (size_t)(2 * pr + 2) * pstride;
      const float4* nB = base + (size_t)(2 * pr + 3) * pstride;
#pragma unroll
      for (int k = 0; k < 4; ++k) {
        nxtA[k] = nA[k * 64 + lane];
        nxtB[k] = nB[k * 64 + lane];
      }
    }

    // two independent norm reductions, interleaved for ILP
    float ssA = 0.f, ssB = 0.f;
#pragma unroll
    for (int k = 0; k < 4; ++k) {
      ssA += dot4(curA[k], curA[k]);
      ssB += dot4(curB[k], curB[k]);
    }
#pragma unroll
    for (int off = 1; off < 64; off <<= 1) {
      ssA += __shfl_xor(ssA, off);
      ssB += __shfl_xor(ssB, off);
    }
    const float wA = 1.0f / fmaxf(sqrtf(ssA), EPS);
    const float wB = 1.0f / fmaxf(sqrtf(ssB), EPS);

#pragma unroll
    for (int k = 0; k < 4; ++k) {
      zs[k].x += curA[k].x + curB[k].x;
      zs[k].y += curA[k].y + curB[k].y;
      zs[k].z += curA[k].z + curB[k].z;
      zs[k].w += curA[k].w + curB[k].w;
      uu[k].x += wA * curA[k].x + wB * curB[k].x;
      uu[k].y += wA * curA[k].y + wB * curB[k].y;
      uu[k].z += wA * curA[k].z + wB * curB[k].z;
      uu[k].w += wA * curA[k].w + wB * curB[k].w;
    }
    if (more) {
#pragma unroll
      for (int k = 0; k < 4; ++k) {
        curA[k] = nxtA[k];
        curB[k] = nxtB[k];
      }
    }
  }

  // cross-wave combine: wave w's float4 index k*64+lane
#pragma unroll
  for (int k = 0; k < 4; ++k) {
    lds_zs[w][k * 64 + lane] = zs[k];
    lds_uu[w][k * 64 + lane] = uu[k];
  }
  __syncthreads();

  // thread t now owns float4 index t (d = 4t..4t+3)
  float4 zsum = make_float4(0.f, 0.f, 0.f, 0.f);
  float4 usum = make_float4(0.f, 0.f, 0.f, 0.f);
#pragma unroll
  for (int ww = 0; ww < WAVES; ++ww) {
    float4 a = lds_zs[ww][t];
    float4 u = lds_uu[ww][t];
    zsum.x += a.x; zsum.y += a.y; zsum.z += a.z; zsum.w += a.w;
    usum.x += u.x; usum.y += u.y; usum.z += u.z; usum.w += u.w;
  }

  // ||z_sum||^2 across the block, broadcast
  float ss = dot4(zsum, zsum);
  ss = wave_reduce_sum(ss);
  if (lane == 0) red[w] = ss;
  __syncthreads();
  ss = red[0] + red[1] + red[2] + red[3];

  // an = (z_sum/P)/max(||z_sum||/P, eps) = z_sum / max(||z_sum||, P*eps)
  const float inv = 1.0f / fmaxf(sqrtf(ss), (float)P * EPS);
  float4 a4 = make_float4(zsum.x * inv, zsum.y * inv, zsum.z * inv, zsum.w * inv);

  ((float4*)an)[(size_t)b * D4 + t] = a4;
  ((float4*)Uv)[(size_t)b * D4 + t] = usum;

  float dg = dot4(usum, a4);
  dg = wave_reduce_sum(dg);
  if (lane == 0) red[WAVES + w] = dg;
  __syncthreads();
  if (t == 0) diag[b] = red[WAVES] + red[WAVES + 1] + red[WAVES + 2] + red[WAVES + 3];
}

// K_tail: 32 blocks. Each block column-sums an/Uv over its 16 b's into its
// OWN partial slot (no contended atomics), fences, bumps the semaphore; the
// last block reduces the 32 partials (agent-scope atomic loads for cross-XCD
// visibility) + diag and writes out = (S.T - sum diag)/count - 1.
__global__ __launch_bounds__(256) void k_tail(const float* __restrict__ an,
                                              const float* __restrict__ Uv,
                                              const float* __restrict__ diag,
                                              float* __restrict__ Spart,
                                              float* __restrict__ Tpart,
                                              int* __restrict__ counter,
                                              float* __restrict__ out) {
  const int blk = blockIdx.x;
  const int t = threadIdx.x;  // owns float4 index t, D4 == 256
  const int w = t >> 6;
  const int lane = t & 63;

  float4 s = make_float4(0.f, 0.f, 0.f, 0.f);
  float4 tt = make_float4(0.f, 0.f, 0.f, 0.f);
#pragma unroll 4
  for (int i = 0; i < BPB; ++i) {
    const size_t b = (size_t)blk * BPB + i;
    float4 a = ((const float4*)an)[b * D4 + t];
    float4 u = ((const float4*)Uv)[b * D4 + t];
    s.x += a.x; s.y += a.y; s.z += a.z; s.w += a.w;
    tt.x += u.x; tt.y += u.y; tt.z += u.z; tt.w += u.w;
  }
  ((float4*)Spart)[(size_t)blk * D4 + t] = s;
  ((float4*)Tpart)[(size_t)blk * D4 + t] = tt;

  // release: make my partial visible, then bump
  __threadfence();
  __syncthreads();
  __shared__ int is_last;
  if (t == 0) {
    int old = atomicAdd(counter, 1);
    is_last = (old == TB - 1);
  }
  __syncthreads();
  if (!is_last) return;

  __threadfence();
  // reduce partials: S[4t+k] = sum over blk of Spart[blk][4t+k]
  float S4[4] = {0.f, 0.f, 0.f, 0.f};
  float T4[4] = {0.f, 0.f, 0.f, 0.f};
  for (int blk2 = 0; blk2 < TB; ++blk2) {
#pragma unroll
    for (int k = 0; k < 4; ++k) {
      S4[k] += __hip_atomic_load(&Spart[(size_t)blk2 * D + 4 * t + k],
                                 __ATOMIC_RELAXED, __HIP_MEMORY_SCOPE_AGENT);
      T4[k] += __hip_atomic_load(&Tpart[(size_t)blk2 * D + 4 * t + k],
                                 __ATOMIC_RELAXED, __HIP_MEMORY_SCOPE_AGENT);
    }
  }
  float local = S4[0] * T4[0] + S4[1] * T4[1] + S4[2] * T4[2] + S4[3] * T4[3];
  // diag written by previous kernel (boundary-visible): plain loads fine
  local -= diag[t] + diag[t + 256];
  local = wave_reduce_sum(local);
  __shared__ float red2[4];
  if (lane == 0) red2[w] = local;
  __syncthreads();
  if (t == 0) {
    const float tot = red2[0] + red2[1] + red2[2] + red2[3];
    const float count = 64.0f * 512.0f * 511.0f;  // P*B*(B-1), exact in fp32
    out[0] = tot / count - 1.0f;
  }
}

extern "C" void kernel_launch(void* const* d_in, const int* in_sizes, int n_in,
                              void* d_out, int out_size, void* d_ws, size_t ws_size,
                              hipStream_t stream) {
  const float* z = (const float*)d_in[0];  // z_list (P,B,D); d_in[1] unused

  float* ws = (float*)d_ws;
  float* an = ws;                                  // B*D
  float* Uv = an + (size_t)B * D;                  // B*D
  float* diag = Uv + (size_t)B * D;                // B
  float* Spart = diag + B;                         // TB*D
  float* Tpart = Spart + (size_t)TB * D;           // TB*D
  int* counter = (int*)(Tpart + (size_t)TB * D);   // 1 int, zeroed by k_main

  k_main<<<B, 256, 0, stream>>>(z, an, Uv, diag, counter);
  k_tail<<<TB, 256, 0, stream>>>(an, Uv, diag, Spart, Tpart, counter, (float*)d_out);
}

// Round 9
// 31.970 us; speedup vs baseline: 2.1005x; 1.5262x over previous
//
#include <hip/hip_runtime.h>
#include <math.h>

// Problem constants (from reference setup_inputs): z_list (P,B,D) fp32
constexpr int P = 64, B = 512, D = 1024;
constexpr int D4 = D / 4;           // 256 float4 per row
constexpr int WAVES = 4;            // waves per block in main kernel
constexpr int PC = P / WAVES;       // 16 p-rows per wave (8 pairs)
constexpr int TB = 32;              // tail blocks (d-split: 8 float4 cols each)
#define EPS 1e-8f

__device__ inline float wave_reduce_sum(float v) {
#pragma unroll
  for (int off = 1; off < 64; off <<= 1) v += __shfl_xor(v, off);
  return v;
}

__device__ inline float dot4(const float4& a, const float4& b) {
  return a.x * b.x + a.y * b.y + a.z * b.z + a.w * b.w;
}

// K_main: one block (4 waves) per b. Each wave streams 16 p-rows of z[:,b,:]
// as 8 row-pairs (depth-1 prefetch, 2 interleaved norm-reduce chains). LDS
// combines the 4 waves; block normalizes mean row -> an[b], writes Uv[b],
// diag[b] = Uv.an. Block 0 zeroes out[0] (tail accumulates into it).
// Measured (R7, REP=3): 27.3 us/pass, ~4.9 TB/s effective read BW.
__global__ __launch_bounds__(256) void k_main(const float* __restrict__ z,
                                              float* __restrict__ an,
                                              float* __restrict__ Uv,
                                              float* __restrict__ diag,
                                              float* __restrict__ out) {
  const int b = blockIdx.x;
  const int t = threadIdx.x;
  const int w = t >> 6;              // wave 0..3
  const int lane = t & 63;

  if (b == 0 && t == 0) out[0] = 0.f;  // boundary-visible to k_tail

  __shared__ float4 lds_zs[WAVES][D4];  // 16 KB
  __shared__ float4 lds_uu[WAVES][D4];  // 16 KB
  __shared__ float red[2 * WAVES];

  float4 zs[4], uu[4];
#pragma unroll
  for (int k = 0; k < 4; ++k) {
    zs[k] = make_float4(0.f, 0.f, 0.f, 0.f);
    uu[k] = make_float4(0.f, 0.f, 0.f, 0.f);
  }

  // wave w handles p = w*PC .. w*PC+PC-1, rows z[p][b][:]
  const size_t pstride = (size_t)B * D4;  // float4 stride between p's
  const float4* base = (const float4*)z + ((size_t)(w * PC) * B + b) * D4;

  float4 curA[4], curB[4];
#pragma unroll
  for (int k = 0; k < 4; ++k) {
    curA[k] = base[k * 64 + lane];
    curB[k] = base[pstride + k * 64 + lane];
  }

  for (int pr = 0; pr < PC / 2; ++pr) {
    float4 nxtA[4], nxtB[4];
    const bool more = (pr + 1 < PC / 2);
    if (more) {
      const float4* nA = base + (size_t)(2 * pr + 2) * pstride;
      const float4* nB = base + (size_t)(2 * pr + 3) * pstride;
#pragma unroll
      for (int k = 0; k < 4; ++k) {
        nxtA[k] = nA[k * 64 + lane];
        nxtB[k] = nB[k * 64 + lane];
      }
    }

    // two independent norm reductions, interleaved for ILP
    float ssA = 0.f, ssB = 0.f;
#pragma unroll
    for (int k = 0; k < 4; ++k) {
      ssA += dot4(curA[k], curA[k]);
      ssB += dot4(curB[k], curB[k]);
    }
#pragma unroll
    for (int off = 1; off < 64; off <<= 1) {
      ssA += __shfl_xor(ssA, off);
      ssB += __shfl_xor(ssB, off);
    }
    const float wA = 1.0f / fmaxf(sqrtf(ssA), EPS);
    const float wB = 1.0f / fmaxf(sqrtf(ssB), EPS);

#pragma unroll
    for (int k = 0; k < 4; ++k) {
      zs[k].x += curA[k].x + curB[k].x;
      zs[k].y += curA[k].y + curB[k].y;
      zs[k].z += curA[k].z + curB[k].z;
      zs[k].w += curA[k].w + curB[k].w;
      uu[k].x += wA * curA[k].x + wB * curB[k].x;
      uu[k].y += wA * curA[k].y + wB * curB[k].y;
      uu[k].z += wA * curA[k].z + wB * curB[k].z;
      uu[k].w += wA * curA[k].w + wB * curB[k].w;
    }
    if (more) {
#pragma unroll
      for (int k = 0; k < 4; ++k) {
        curA[k] = nxtA[k];
        curB[k] = nxtB[k];
      }
    }
  }

  // cross-wave combine: wave w's float4 index k*64+lane
#pragma unroll
  for (int k = 0; k < 4; ++k) {
    lds_zs[w][k * 64 + lane] = zs[k];
    lds_uu[w][k * 64 + lane] = uu[k];
  }
  __syncthreads();

  // thread t now owns float4 index t (d = 4t..4t+3)
  float4 zsum = make_float4(0.f, 0.f, 0.f, 0.f);
  float4 usum = make_float4(0.f, 0.f, 0.f, 0.f);
#pragma unroll
  for (int ww = 0; ww < WAVES; ++ww) {
    float4 a = lds_zs[ww][t];
    float4 u = lds_uu[ww][t];
    zsum.x += a.x; zsum.y += a.y; zsum.z += a.z; zsum.w += a.w;
    usum.x += u.x; usum.y += u.y; usum.z += u.z; usum.w += u.w;
  }

  // ||z_sum||^2 across the block, broadcast
  float ss = dot4(zsum, zsum);
  ss = wave_reduce_sum(ss);
  if (lane == 0) red[w] = ss;
  __syncthreads();
  ss = red[0] + red[1] + red[2] + red[3];

  // an = (z_sum/P)/max(||z_sum||/P, eps) = z_sum / max(||z_sum||, P*eps)
  const float inv = 1.0f / fmaxf(sqrtf(ss), (float)P * EPS);
  float4 a4 = make_float4(zsum.x * inv, zsum.y * inv, zsum.z * inv, zsum.w * inv);

  ((float4*)an)[(size_t)b * D4 + t] = a4;
  ((float4*)Uv)[(size_t)b * D4 + t] = usum;

  float dg = dot4(usum, a4);
  dg = wave_reduce_sum(dg);
  if (lane == 0) red[WAVES + w] = dg;
  __syncthreads();
  if (t == 0) diag[b] = red[WAVES] + red[WAVES + 1] + red[WAVES + 2] + red[WAVES + 3];
}

// K_tail: 32 blocks, d-split. Block blk owns float4-columns [blk*8, blk*8+8)
// (32 scalar cols). Thread t: f4col = t&7, rowgroup = t>>3; accumulates
// S4/T4 over rows r = rowgroup + 32*i. Wave shfl (offsets 8/16/32) + LDS
// combine complete the column sums; threads 0..7 dot them; block adds ONE
// scalar to out[0] (33 total adds -> no contention; R5/R8 lesson applied).
__global__ __launch_bounds__(256) void k_tail(const float* __restrict__ an,
                                              const float* __restrict__ Uv,
                                              const float* __restrict__ diag,
                                              float* __restrict__ out) {
  const int blk = blockIdx.x;
  const int t = threadIdx.x;
  const int w = t >> 6;
  const int lane = t & 63;
  const int f4c = blk * 8 + (t & 7);   // this thread's float4 column
  const int rg = t >> 3;               // rowgroup 0..31

  float4 S = make_float4(0.f, 0.f, 0.f, 0.f);
  float4 T = make_float4(0.f, 0.f, 0.f, 0.f);
#pragma unroll 4
  for (int i = 0; i < 16; ++i) {
    const size_t r = (size_t)rg + 32 * i;   // rows rg, rg+32, ..., rg+480
    float4 a = ((const float4*)an)[r * D4 + f4c];
    float4 u = ((const float4*)Uv)[r * D4 + f4c];
    S.x += a.x; S.y += a.y; S.z += a.z; S.w += a.w;
    T.x += u.x; T.y += u.y; T.z += u.z; T.w += u.w;
  }

  // reduce over the 8 rowgroups within this wave (lanes sharing lane&7)
#pragma unroll
  for (int off = 8; off < 64; off <<= 1) {
    S.x += __shfl_xor(S.x, off); S.y += __shfl_xor(S.y, off);
    S.z += __shfl_xor(S.z, off); S.w += __shfl_xor(S.w, off);
    T.x += __shfl_xor(T.x, off); T.y += __shfl_xor(T.y, off);
    T.z += __shfl_xor(T.z, off); T.w += __shfl_xor(T.w, off);
  }

  // combine the 4 waves via LDS
  __shared__ float4 ldsS[4][8], ldsT[4][8];
  if (lane < 8) {
    ldsS[w][lane] = S;
    ldsT[w][lane] = T;
  }
  __syncthreads();

  float dotp = 0.f;
  if (t < 8) {
    float4 Sf = ldsS[0][t], Tf = ldsT[0][t];
#pragma unroll
    for (int ww = 1; ww < 4; ++ww) {
      float4 s2 = ldsS[ww][t], t2 = ldsT[ww][t];
      Sf.x += s2.x; Sf.y += s2.y; Sf.z += s2.z; Sf.w += s2.w;
      Tf.x += t2.x; Tf.y += t2.y; Tf.z += t2.z; Tf.w += t2.w;
    }
    dotp = dot4(Sf, Tf);
  }
  // diag slice: 16 b's per block, lanes 16..31 of wave 0
  float dgp = 0.f;
  if (t >= 16 && t < 32) dgp = diag[blk * 16 + (t - 16)];

  if (w == 0) {
    float v = dotp - dgp;
    // sum lanes 0..31 (dot in 0..7, diag in 16..31): offsets 1,2,4,8,16
#pragma unroll
    for (int off = 1; off < 32; off <<= 1) v += __shfl_xor(v, off);
    if (t == 0) {
      const float count = 64.0f * 512.0f * 511.0f;  // P*B*(B-1)
      float contrib = v / count + (blk == 0 ? -1.0f : 0.0f);
      atomicAdd(out, contrib);
    }
  }
}

extern "C" void kernel_launch(void* const* d_in, const int* in_sizes, int n_in,
                              void* d_out, int out_size, void* d_ws, size_t ws_size,
                              hipStream_t stream) {
  const float* z = (const float*)d_in[0];  // z_list (P,B,D); d_in[1] unused

  float* ws = (float*)d_ws;
  float* an = ws;                                  // B*D (2 MB)
  float* Uv = an + (size_t)B * D;                  // B*D (2 MB)
  float* diag = Uv + (size_t)B * D;                // B

  k_main<<<B, 256, 0, stream>>>(z, an, Uv, diag, (float*)d_out);
  k_tail<<<TB, 256, 0, stream>>>(an, Uv, diag, (float*)d_out);
}